// Round 4
// baseline (252.362 us; speedup 1.0000x reference)
//
#include <hip/hip_runtime.h>
#include <cmath>

#define BN 2
#define AN 3
#define SN 8
#define CN 20
#define IMGN 256
#define NSTEP 384   // A*S*S*B steps in scan order (k,i,j,b)
#define PRED_C 26   // 6 + C
#define NE (NSTEP * 6)

__device__ __forceinline__ float wredf(float v){
  #pragma unroll
  for (int o = 32; o; o >>= 1) v += __shfl_xor(v, o);
  return v;
}
__device__ __forceinline__ double wredd(double v){
  #pragma unroll
  for (int o = 32; o; o >>= 1) v += __shfl_xor(v, o);
  return v;
}
// rocPRIM-style gfx9 DPP wave sum: result valid in lane 63. Pure VALU, no LDS pipe.
__device__ __forceinline__ float wsum_dpp(float x){
  x += __int_as_float(__builtin_amdgcn_update_dpp(0, __float_as_int(x), 0x111, 0xf, 0xf, false)); // row_shr:1
  x += __int_as_float(__builtin_amdgcn_update_dpp(0, __float_as_int(x), 0x112, 0xf, 0xf, false)); // row_shr:2
  x += __int_as_float(__builtin_amdgcn_update_dpp(0, __float_as_int(x), 0x114, 0xf, 0xf, false)); // row_shr:4
  x += __int_as_float(__builtin_amdgcn_update_dpp(0, __float_as_int(x), 0x118, 0xf, 0xf, false)); // row_shr:8
  x += __int_as_float(__builtin_amdgcn_update_dpp(0, __float_as_int(x), 0x142, 0xa, 0xf, false)); // row_bcast:15
  x += __int_as_float(__builtin_amdgcn_update_dpp(0, __float_as_int(x), 0x143, 0xc, 0xf, false)); // row_bcast:31
  return x;
}
__device__ __forceinline__ int finitef(float x){
  return (__float_as_uint(x) & 0x7f800000u) != 0x7f800000u;
}
// exact replica of reference _axis_mask index computation (f32 trunc + negative wrap)
__device__ __forceinline__ unsigned axism(float lo, float hi){
  float lof = truncf(fminf(fmaxf(lo, -1e9f), 1e9f));
  float hif = truncf(fminf(fmaxf(hi, -1e9f), 1e9f));
  int l = (int)lof, h = (int)hif;
  l = (l < 0) ? max(IMGN + l, 0) : min(l, IMGN);
  h = (h < 0) ? max(IMGN + h, 0) : min(h, IMGN);
  return (unsigned)l | ((unsigned)h << 16);
}

// per-step scan parameters; scan order t = ((k*S + i)*S + j)*B + b
__device__ __forceinline__ void step_params(int t, const float* __restrict__ pred,
                                            const float* __restrict__ anc,
                                            unsigned* valid, float* lv,
                                            unsigned* fx, unsigned* fy,
                                            unsigned* sx, unsigned* sy){
  int b = t % BN;
  int j = (t / BN) % SN;
  int i = (t / (BN * SN)) % SN;
  int k = t / (BN * SN * SN);
  const float* pc = pred + (size_t)((((b * AN + k) * SN + i) * SN + j)) * PRED_C;
  float x = pc[1], y = pc[2], wv = pc[3], hv = pc[4], v = pc[5];
  float aw = anc[2 * k], ah = anc[2 * k + 1];
  // xy gets sigmoid applied (k+2) times total (1 before loop + k+1 in loop)
  for (int m = 0; m < k + 2; ++m) {
    x = 1.0f / (1.0f + expf(-x));
    y = 1.0f / (1.0f + expf(-y));
  }
  // wh: (k+1) iterations of exp(.)*anchor[k], in f32 (overflow -> inf -> invalid)
  for (int m = 0; m < k + 1; ++m) {
    wv = expf(wv) * aw;
    hv = expf(hv) * ah;
  }
  float cx = (x + (float)j) / 8.0f * 256.0f;
  float cy = (y + (float)i) / 8.0f * 256.0f;
  float w  = wv / 8.0f * 256.0f;
  float h  = hv / 8.0f * 256.0f;
  *valid = (w > 0.0f) && (h > 0.0f) && finitef(w) && finitef(h);
  *lv = logf(fmaxf(1.0f, v));
  // NOTE reference quirk: x-mask (from cx,w) indexes dp's ROW axis, y-mask the COL axis
  *fx = axism(cx - w / 2.0f, cx + w / 2.0f);
  *fy = axism(cy - h / 2.0f, cy + h / 2.0f);
  *sx = axism(cx - w / 4.0f, cx + w / 4.0f);
  *sy = axism(cy - h / 4.0f, cy + h / 4.0f);
}

// ---------------- Kernel B: per-pixel step scan -> per-step deltas via global atomics ----------------
// grid must be exactly BN*IMGN blocks; red[NE] pre-zeroed.
__global__ __launch_bounds__(256) void yolo_kB(const float* __restrict__ pred,
                                               const float* __restrict__ anc,
                                               const float* __restrict__ depth,
                                               float* __restrict__ red){
  __shared__ uint2    s_rxx[NSTEP];       // (fx, sx) row-bound packs
  __shared__ uint2    s_cyy[NSTEP];       // (fy, sy) col-bound packs
  __shared__ float    s_lv[NSTEP];
  __shared__ unsigned s_list[NSTEP / 2];  // compacted row-active steps (ordered)
  __shared__ int      s_nact;

  int tid = threadIdx.x;
  for (int t = tid; t < NSTEP; t += 256) {
    unsigned vld, fx, fy, sx, sy; float lv;
    step_params(t, pred, anc, &vld, &lv, &fx, &fy, &sx, &sy);
    if (!vld) { fx = 0xFFFFu; sx = 0xFFFFu; }   // lo=0xFFFF,hi=0 -> empty row range
    s_rxx[t] = make_uint2(fx, sx);
    s_cyy[t] = make_uint2(fy, sy);
    s_lv[t] = lv;
  }
  __syncthreads();

  int ru = blockIdx.x;          // one row-unit per block
  int b = ru >> 8, r = ru & 255;
  int c = tid, ln = tid & 63;

  // wave 0: ordered compaction of steps whose rect touches row r (row test is block-uniform)
  if (tid < 64) {
    int cnt = 0;
    #pragma unroll
    for (int g = 0; g < 3; ++g) {
      int m = g * 64 + ln;                 // m in [0,192)
      int t = b + 2 * m;                   // steps of batch b
      uint2 rx = s_rxx[t];
      bool rowF = (r >= (int)(rx.x & 0xffffu)) && (r < (int)(rx.x >> 16));
      bool rowS = (r >= (int)(rx.y & 0xffffu)) && (r < (int)(rx.y >> 16));
      bool f = rowF || rowS;
      unsigned long long msk = __ballot(f);
      int pos = (int)__popcll(msk & ((1ull << ln) - 1ull));
      if (f) s_list[cnt + pos] = (unsigned)t | (rowF ? 512u : 0u) | (rowS ? 1024u : 0u);
      cnt += (int)__popcll(msk);
    }
    if (ln == 0) s_nact = cnt;
  }

  float dt = depth[(size_t)ru * IMGN + c];
  bool okp = dt >= 1.0f;
  float ldt = okp ? logf(dt) : 0.0f;
  __syncthreads();
  int nact = s_nact;

  bool hF = false, hS = false;
  float lvF = 0.0f, lvS = 0.0f;
  for (int idx = 0; idx < nact; ++idx) {
    unsigned ent = s_list[idx];
    int t = (int)(ent & 511u);
    bool rowF = (ent & 512u) != 0u;
    bool rowS = (ent & 1024u) != 0u;
    uint2 cyb = s_cyy[t];
    float lv = s_lv[t];
    bool inF = okp && rowF && (c >= (int)(cyb.x & 0xffffu)) && (c < (int)(cyb.x >> 16));
    bool inS = okp && rowS && (c >= (int)(cyb.y & 0xffffu)) && (c < (int)(cyb.y >> 16));
    if (__ballot(inF || inS) == 0ull) continue;
    unsigned long long mF = __ballot(inF && !hF);   // first paints (pre-update)
    unsigned long long mS = __ballot(inS && !hS);
    float d1 = 0.f, d2 = 0.f, e1 = 0.f, e2 = 0.f;
    if (inF) {
      float gn = lv - ldt;
      if (hF) { float go = lvF - ldt; d1 = lv - lvF; d2 = gn * gn - go * go; }
      else    { d1 = gn; d2 = gn * gn; hF = true; }
      lvF = lv;
    }
    if (inS) {
      float gn = lv - ldt;
      if (hS) { float go = lvS - ldt; e1 = lv - lvS; e2 = gn * gn - go * go; }
      else    { e1 = gn; e2 = gn * gn; hS = true; }
      lvS = lv;
    }
    d1 = wsum_dpp(d1); d2 = wsum_dpp(d2);
    e1 = wsum_dpp(e1); e2 = wsum_dpp(e2);
    if (ln == 63) {
      float* base = red + t * 6;
      float c0 = (float)__popcll(mF), c3 = (float)__popcll(mS);
      if (c0 != 0.f) atomicAdd(base + 0, c0);
      if (d1 != 0.f) atomicAdd(base + 1, d1);
      if (d2 != 0.f) atomicAdd(base + 2, d2);
      if (c3 != 0.f) atomicAdd(base + 3, c3);
      if (e1 != 0.f) atomicAdd(base + 4, e1);
      if (e2 != 0.f) atomicAdd(base + 5, e2);
    }
  }
}

// ---------------- Kernel C: YOLO losses + prefix over steps + final loss ----------------
__global__ __launch_bounds__(384) void yolo_kC(const float* __restrict__ pred,
                                               const float* __restrict__ tgt,
                                               const float* __restrict__ anc,
                                               const float* __restrict__ red,
                                               float* __restrict__ out){
  __shared__ double sd[NE];
  __shared__ double chunk[6 * 6];     // [chunkIdx][comp], chunks of 64 steps
  __shared__ double rl[6], rc[6];
  __shared__ float  ry[6 * 6];
  int tid = threadIdx.x;
  for (int e = tid; e < NE; e += 384) sd[e] = (double)red[e];

  // ---- YOLO losses; cell order (b,a,i,j) ----
  float s_obj, s_bce, s_bcecnt, s_objls, s_boxls, s_clsls;
  {
    int t = tid;
    int j = t % SN;
    int i = (t / SN) % SN;
    int a = (t / (SN * SN)) % AN;
    int b = t / (SN * SN * AN);
    const float* pc = pred + (size_t)((((b * AN + a) * SN + i) * SN + j)) * PRED_C;
    const float* tc = tgt  + (size_t)((((b * AN + a) * SN + i) * SN + j)) * 6;
    float t0 = tc[0];
    float objf  = (t0 == 1.0f) ? 1.0f : 0.0f;
    float noobj = (t0 == 0.0f) ? 1.0f : 0.0f;
    float p0 = pc[0];
    float l = fmaxf(p0, 0.0f) - p0 * t0 + log1pf(expf(-fabsf(p0)));
    s_bce = l * noobj; s_bcecnt = noobj; s_obj = objf;
    float aw = anc[2 * a], ah = anc[2 * a + 1];
    float sxp = 1.0f / (1.0f + expf(-pc[1]));
    float syp = 1.0f / (1.0f + expf(-pc[2]));
    float bw = expf(pc[3]) * aw, bh = expf(pc[4]) * ah;
    float ax1 = sxp - bw * 0.5f, ax2 = sxp + bw * 0.5f;
    float ay1 = syp - bh * 0.5f, ay2 = syp + bh * 0.5f;
    float bx1 = tc[1] - tc[3] * 0.5f, bx2 = tc[1] + tc[3] * 0.5f;
    float by1 = tc[2] - tc[4] * 0.5f, by2 = tc[2] + tc[4] * 0.5f;
    float iw = fmaxf(fminf(ax2, bx2) - fmaxf(ax1, bx1), 0.0f);
    float ih = fmaxf(fminf(ay2, by2) - fmaxf(ay1, by1), 0.0f);
    float inter = iw * ih;
    float areaA = fabsf((ax2 - ax1) * (ay2 - ay1));
    float areaB = fabsf((bx2 - bx1) * (by2 - by1));
    float iou = inter / (areaA + areaB - inter + 1e-6f);
    float sp0 = 1.0f / (1.0f + expf(-p0));
    float od = sp0 - iou * t0;
    s_objls = od * od * objf;
    float dx = sxp - tc[1], dy = syp - tc[2];
    float dw = pc[3] - logf(1e-16f + tc[3] / aw);
    float dh = pc[4] - logf(1e-16f + tc[4] / ah);
    s_boxls = (dx * dx + dy * dy + dw * dw + dh * dh) * objf;
    int lbl = (int)tc[5];
    float mx = -INFINITY;
    for (int c = 0; c < CN; ++c) mx = fmaxf(mx, pc[6 + c]);
    float se = 0.0f;
    for (int c = 0; c < CN; ++c) se += expf(pc[6 + c] - mx);
    float nll = mx + logf(se) - pc[6 + lbl];
    s_clsls = nll * objf;
  }
  {
    int wv = tid >> 6, ln = tid & 63;
    float vals[6] = { s_obj, s_bce, s_bcecnt, s_objls, s_boxls, s_clsls };
    #pragma unroll
    for (int ci = 0; ci < 6; ++ci) {
      float v = wredf(vals[ci]);
      if (ln == 0) ry[ci * 6 + wv] = v;
    }
  }

  // ---- valid bit for step tid (recomputed; only w/h chain matters) ----
  unsigned vld, ufx, ufy, usx, usy; float ulv;
  step_params(tid, pred, anc, &vld, &ulv, &ufx, &ufy, &usx, &usy);

  __syncthreads();
  if (tid < 36) {
    int ch = tid / 6, comp = tid % 6;
    double s = 0.0;
    for (int t = ch * 64; t < ch * 64 + 64; ++t) s += sd[t * 6 + comp];
    chunk[tid] = s;
  }
  __syncthreads();

  int t = tid;
  int ch = t >> 6;
  double P[6];
  #pragma unroll
  for (int comp = 0; comp < 6; ++comp) {
    double s = 0.0;
    for (int cc = 0; cc < ch; ++cc) s += chunk[cc * 6 + comp];
    for (int tt = (ch << 6); tt <= t; ++tt) s += sd[tt * 6 + comp];
    P[comp] = s;   // inclusive prefix: sums AFTER step t's paint
  }
  double lossd = 0.0, cntd = 0.0;
  {
    double n = P[0], Sg = P[1], Sg2 = P[2];
    double mean = Sg / fmax(n, 1.0);
    double var = (Sg2 - 2.0 * mean * Sg + n * mean * mean) / fmax(n - 1.0, 1.0);
    double Dg = var + 0.15 * mean * mean;
    double pl = 10.0 * sqrt(fmax(Dg, 1e-30));
    if (vld && n >= 2.0) { lossd += pl; cntd += 1.0; }
  }
  {
    double n = P[3], Sg = P[4], Sg2 = P[5];
    double mean = Sg / fmax(n, 1.0);
    double var = (Sg2 - 2.0 * mean * Sg + n * mean * mean) / fmax(n - 1.0, 1.0);
    double Dg = var + 0.15 * mean * mean;
    double pl = 10.0 * sqrt(fmax(Dg, 1e-30));
    if (vld && n >= 2.0) { lossd += pl; cntd += 1.0; }
  }
  int wv = tid >> 6, ln = tid & 63;
  double L = wredd(lossd), C = wredd(cntd);
  if (ln == 0) { rl[wv] = L; rc[wv] = C; }
  __syncthreads();
  if (tid == 0) {
    double totL = 0.0, totC = 0.0;
    for (int i = 0; i < 6; ++i) { totL += rl[i]; totC += rc[i]; }
    float yolo[6];
    #pragma unroll
    for (int ci = 0; ci < 6; ++ci) {
      float s = 0.0f;
      for (int w2 = 0; w2 < 6; ++w2) s += ry[ci * 6 + w2];
      yolo[ci] = s;
    }
    float dl = (float)(totL / fmax(totC, 1.0));
    float nobj = fmaxf(yolo[0], 1.0f);
    float noo  = yolo[1] / fmaxf(yolo[2], 1.0f);
    float objl = yolo[3] / nobj;
    float boxl = yolo[4] / (nobj * 4.0f);
    float clsl = yolo[5] / nobj;
    out[0] = 10.0f * boxl + objl + 10.0f * noo + clsl + dl;
  }
}

extern "C" void kernel_launch(void* const* d_in, const int* in_sizes, int n_in,
                              void* d_out, int out_size, void* d_ws, size_t ws_size,
                              hipStream_t stream) {
  const float* pred  = (const float*)d_in[0];
  const float* tgt   = (const float*)d_in[1];
  const float* anc   = (const float*)d_in[2];
  const float* depth = (const float*)d_in[3];

  float* red = (float*)d_ws;     // NE floats = 9216 B
  hipMemsetAsync(red, 0, NE * sizeof(float), stream);
  hipLaunchKernelGGL(yolo_kB, dim3(BN * IMGN), dim3(256), 0, stream, pred, anc, depth, red);
  hipLaunchKernelGGL(yolo_kC, dim3(1), dim3(384), 0, stream, pred, tgt, anc, red, (float*)d_out);
}

// Round 5
// 141.551 us; speedup vs baseline: 1.7828x; 1.7828x over previous
//
#include <hip/hip_runtime.h>
#include <cmath>

#define BN 2
#define AN 3
#define SN 8
#define CN 20
#define IMGN 256
#define NSTEP 384   // A*S*S*B steps in scan order (k,i,j,b)
#define PRED_C 26   // 6 + C
#define NE (NSTEP * 6)
#define NB (BN * IMGN)   // 512 kB blocks, one row-unit each

__device__ __forceinline__ float wredf(float v){
  #pragma unroll
  for (int o = 32; o; o >>= 1) v += __shfl_xor(v, o);
  return v;
}
__device__ __forceinline__ double wredd(double v){
  #pragma unroll
  for (int o = 32; o; o >>= 1) v += __shfl_xor(v, o);
  return v;
}
// rocPRIM-style gfx9 DPP wave sum: result valid in lane 63. Pure VALU, no LDS pipe.
// (correctness HW-verified in round 4: absmax 0.0)
__device__ __forceinline__ float wsum_dpp(float x){
  x += __int_as_float(__builtin_amdgcn_update_dpp(0, __float_as_int(x), 0x111, 0xf, 0xf, false)); // row_shr:1
  x += __int_as_float(__builtin_amdgcn_update_dpp(0, __float_as_int(x), 0x112, 0xf, 0xf, false)); // row_shr:2
  x += __int_as_float(__builtin_amdgcn_update_dpp(0, __float_as_int(x), 0x114, 0xf, 0xf, false)); // row_shr:4
  x += __int_as_float(__builtin_amdgcn_update_dpp(0, __float_as_int(x), 0x118, 0xf, 0xf, false)); // row_shr:8
  x += __int_as_float(__builtin_amdgcn_update_dpp(0, __float_as_int(x), 0x142, 0xa, 0xf, false)); // row_bcast:15
  x += __int_as_float(__builtin_amdgcn_update_dpp(0, __float_as_int(x), 0x143, 0xc, 0xf, false)); // row_bcast:31
  return x;
}
__device__ __forceinline__ int finitef(float x){
  return (__float_as_uint(x) & 0x7f800000u) != 0x7f800000u;
}
// exact replica of reference _axis_mask index computation (f32 trunc + negative wrap)
__device__ __forceinline__ unsigned axism(float lo, float hi){
  float lof = truncf(fminf(fmaxf(lo, -1e9f), 1e9f));
  float hif = truncf(fminf(fmaxf(hi, -1e9f), 1e9f));
  int l = (int)lof, h = (int)hif;
  l = (l < 0) ? max(IMGN + l, 0) : min(l, IMGN);
  h = (h < 0) ? max(IMGN + h, 0) : min(h, IMGN);
  return (unsigned)l | ((unsigned)h << 16);
}

// per-step scan parameters; scan order t = ((k*S + i)*S + j)*B + b
__device__ __forceinline__ void step_params(int t, const float* __restrict__ pred,
                                            const float* __restrict__ anc,
                                            unsigned* valid, float* lv,
                                            unsigned* fx, unsigned* fy,
                                            unsigned* sx, unsigned* sy){
  int b = t % BN;
  int j = (t / BN) % SN;
  int i = (t / (BN * SN)) % SN;
  int k = t / (BN * SN * SN);
  const float* pc = pred + (size_t)((((b * AN + k) * SN + i) * SN + j)) * PRED_C;
  float x = pc[1], y = pc[2], wv = pc[3], hv = pc[4], v = pc[5];
  float aw = anc[2 * k], ah = anc[2 * k + 1];
  // xy gets sigmoid applied (k+2) times total (1 before loop + k+1 in loop)
  for (int m = 0; m < k + 2; ++m) {
    x = 1.0f / (1.0f + expf(-x));
    y = 1.0f / (1.0f + expf(-y));
  }
  // wh: (k+1) iterations of exp(.)*anchor[k], in f32 (overflow -> inf -> invalid)
  for (int m = 0; m < k + 1; ++m) {
    wv = expf(wv) * aw;
    hv = expf(hv) * ah;
  }
  float cx = (x + (float)j) / 8.0f * 256.0f;
  float cy = (y + (float)i) / 8.0f * 256.0f;
  float w  = wv / 8.0f * 256.0f;
  float h  = hv / 8.0f * 256.0f;
  *valid = (w > 0.0f) && (h > 0.0f) && finitef(w) && finitef(h);
  *lv = logf(fmaxf(1.0f, v));
  // NOTE reference quirk: x-mask (from cx,w) indexes dp's ROW axis, y-mask the COL axis
  *fx = axism(cx - w / 2.0f, cx + w / 2.0f);
  *fy = axism(cy - h / 2.0f, cy + h / 2.0f);
  *sx = axism(cx - w / 4.0f, cx + w / 4.0f);
  *sy = axism(cy - h / 4.0f, cy + h / 4.0f);
}

// ---------------- Kernel B: per-pixel step scan -> per-block per-step delta partials ----------------
// one row-unit per block; sink = per-block LDS accumulator (no global atomics!),
// then one coalesced 9216 B scratch write: scratch[bk * NE + e]
__global__ __launch_bounds__(256) void yolo_kB(const float* __restrict__ pred,
                                               const float* __restrict__ anc,
                                               const float* __restrict__ depth,
                                               float* __restrict__ scratch){
  __shared__ uint2    s_rxx[NSTEP];       // (fx, sx) row-bound packs
  __shared__ uint2    s_cyy[NSTEP];       // (fy, sy) col-bound packs
  __shared__ float    s_lv[NSTEP];
  __shared__ unsigned s_list[NSTEP / 2];  // compacted row-active steps (ordered)
  __shared__ int      s_nact;
  __shared__ float    s_acc[NE];          // per-block accumulator (LDS atomics, 4 writers max)

  int tid = threadIdx.x;
  for (int t = tid; t < NSTEP; t += 256) {
    unsigned vld, fx, fy, sx, sy; float lv;
    step_params(t, pred, anc, &vld, &lv, &fx, &fy, &sx, &sy);
    if (!vld) { fx = 0xFFFFu; sx = 0xFFFFu; }   // lo=0xFFFF,hi=0 -> empty row range
    s_rxx[t] = make_uint2(fx, sx);
    s_cyy[t] = make_uint2(fy, sy);
    s_lv[t] = lv;
  }
  for (int e = tid; e < NE; e += 256) s_acc[e] = 0.0f;
  __syncthreads();

  int ru = blockIdx.x;          // one row-unit per block
  int b = ru >> 8, r = ru & 255;
  int c = tid, ln = tid & 63;

  // wave 0: ordered compaction of steps whose rect touches row r (row test is block-uniform)
  if (tid < 64) {
    int cnt = 0;
    #pragma unroll
    for (int g = 0; g < 3; ++g) {
      int m = g * 64 + ln;                 // m in [0,192)
      int t = b + 2 * m;                   // steps of batch b
      uint2 rx = s_rxx[t];
      bool rowF = (r >= (int)(rx.x & 0xffffu)) && (r < (int)(rx.x >> 16));
      bool rowS = (r >= (int)(rx.y & 0xffffu)) && (r < (int)(rx.y >> 16));
      bool f = rowF || rowS;
      unsigned long long msk = __ballot(f);
      int pos = (int)__popcll(msk & ((1ull << ln) - 1ull));
      if (f) s_list[cnt + pos] = (unsigned)t | (rowF ? 512u : 0u) | (rowS ? 1024u : 0u);
      cnt += (int)__popcll(msk);
    }
    if (ln == 0) s_nact = cnt;
  }

  float dt = depth[(size_t)ru * IMGN + c];
  bool okp = dt >= 1.0f;
  float ldt = okp ? logf(dt) : 0.0f;
  __syncthreads();
  int nact = s_nact;

  bool hF = false, hS = false;
  float lvF = 0.0f, lvS = 0.0f;
  for (int idx = 0; idx < nact; ++idx) {
    unsigned ent = s_list[idx];
    int t = (int)(ent & 511u);
    bool rowF = (ent & 512u) != 0u;
    bool rowS = (ent & 1024u) != 0u;
    uint2 cyb = s_cyy[t];
    float lv = s_lv[t];
    bool inF = okp && rowF && (c >= (int)(cyb.x & 0xffffu)) && (c < (int)(cyb.x >> 16));
    bool inS = okp && rowS && (c >= (int)(cyb.y & 0xffffu)) && (c < (int)(cyb.y >> 16));
    if (__ballot(inF || inS) == 0ull) continue;
    unsigned long long mF = __ballot(inF && !hF);   // first paints (pre-update)
    unsigned long long mS = __ballot(inS && !hS);
    float d1 = 0.f, d2 = 0.f, e1 = 0.f, e2 = 0.f;
    if (inF) {
      float gn = lv - ldt;
      if (hF) { float go = lvF - ldt; d1 = lv - lvF; d2 = gn * gn - go * go; }
      else    { d1 = gn; d2 = gn * gn; hF = true; }
      lvF = lv;
    }
    if (inS) {
      float gn = lv - ldt;
      if (hS) { float go = lvS - ldt; e1 = lv - lvS; e2 = gn * gn - go * go; }
      else    { e1 = gn; e2 = gn * gn; hS = true; }
      lvS = lv;
    }
    d1 = wsum_dpp(d1); d2 = wsum_dpp(d2);
    e1 = wsum_dpp(e1); e2 = wsum_dpp(e2);
    if (ln == 63) {
      float* base = s_acc + t * 6;
      float c0 = (float)__popcll(mF), c3 = (float)__popcll(mS);
      if (c0 != 0.f) atomicAdd(base + 0, c0);
      if (d1 != 0.f) atomicAdd(base + 1, d1);
      if (d2 != 0.f) atomicAdd(base + 2, d2);
      if (c3 != 0.f) atomicAdd(base + 3, c3);
      if (e1 != 0.f) atomicAdd(base + 4, e1);
      if (e2 != 0.f) atomicAdd(base + 5, e2);
    }
  }
  __syncthreads();
  // contiguous coalesced write: 9216 B per block
  for (int e = tid; e < NE; e += 256)
    scratch[(size_t)blockIdx.x * NE + e] = s_acc[e];
}

// ---------------- Kernel R: parallel reduce over kB blocks ----------------
// one wave per element e; lanes stride over blocks (reads mostly L2-resident)
__global__ __launch_bounds__(256) void yolo_kR(const float* __restrict__ scratch,
                                               double* __restrict__ reduced){
  int w = threadIdx.x >> 6, ln = threadIdx.x & 63;
  int e = blockIdx.x * 4 + w;            // grid = NE/4 = 576
  double s = 0.0;
  for (int bk = ln; bk < NB; bk += 64)
    s += (double)scratch[(size_t)bk * NE + e];
  s = wredd(s);
  if (ln == 0) reduced[e] = s;
}

// ---------------- Kernel C: YOLO losses + prefix over steps + final loss ----------------
__global__ __launch_bounds__(384) void yolo_kC(const float* __restrict__ pred,
                                               const float* __restrict__ tgt,
                                               const float* __restrict__ anc,
                                               const double* __restrict__ reduced,
                                               float* __restrict__ out){
  __shared__ double sd[NE];
  __shared__ double chunk[6 * 6];     // [chunkIdx][comp], chunks of 64 steps
  __shared__ double rl[6], rc[6];
  __shared__ float  ry[6 * 6];
  int tid = threadIdx.x;
  for (int e = tid; e < NE; e += 384) sd[e] = reduced[e];

  // ---- YOLO losses; cell order (b,a,i,j) ----
  float s_obj, s_bce, s_bcecnt, s_objls, s_boxls, s_clsls;
  {
    int t = tid;
    int j = t % SN;
    int i = (t / SN) % SN;
    int a = (t / (SN * SN)) % AN;
    int b = t / (SN * SN * AN);
    const float* pc = pred + (size_t)((((b * AN + a) * SN + i) * SN + j)) * PRED_C;
    const float* tc = tgt  + (size_t)((((b * AN + a) * SN + i) * SN + j)) * 6;
    float t0 = tc[0];
    float objf  = (t0 == 1.0f) ? 1.0f : 0.0f;
    float noobj = (t0 == 0.0f) ? 1.0f : 0.0f;
    float p0 = pc[0];
    float l = fmaxf(p0, 0.0f) - p0 * t0 + log1pf(expf(-fabsf(p0)));
    s_bce = l * noobj; s_bcecnt = noobj; s_obj = objf;
    float aw = anc[2 * a], ah = anc[2 * a + 1];
    float sxp = 1.0f / (1.0f + expf(-pc[1]));
    float syp = 1.0f / (1.0f + expf(-pc[2]));
    float bw = expf(pc[3]) * aw, bh = expf(pc[4]) * ah;
    float ax1 = sxp - bw * 0.5f, ax2 = sxp + bw * 0.5f;
    float ay1 = syp - bh * 0.5f, ay2 = syp + bh * 0.5f;
    float bx1 = tc[1] - tc[3] * 0.5f, bx2 = tc[1] + tc[3] * 0.5f;
    float by1 = tc[2] - tc[4] * 0.5f, by2 = tc[2] + tc[4] * 0.5f;
    float iw = fmaxf(fminf(ax2, bx2) - fmaxf(ax1, bx1), 0.0f);
    float ih = fmaxf(fminf(ay2, by2) - fmaxf(ay1, by1), 0.0f);
    float inter = iw * ih;
    float areaA = fabsf((ax2 - ax1) * (ay2 - ay1));
    float areaB = fabsf((bx2 - bx1) * (by2 - by1));
    float iou = inter / (areaA + areaB - inter + 1e-6f);
    float sp0 = 1.0f / (1.0f + expf(-p0));
    float od = sp0 - iou * t0;
    s_objls = od * od * objf;
    float dx = sxp - tc[1], dy = syp - tc[2];
    float dw = pc[3] - logf(1e-16f + tc[3] / aw);
    float dh = pc[4] - logf(1e-16f + tc[4] / ah);
    s_boxls = (dx * dx + dy * dy + dw * dw + dh * dh) * objf;
    int lbl = (int)tc[5];
    float mx = -INFINITY;
    for (int c = 0; c < CN; ++c) mx = fmaxf(mx, pc[6 + c]);
    float se = 0.0f;
    for (int c = 0; c < CN; ++c) se += expf(pc[6 + c] - mx);
    float nll = mx + logf(se) - pc[6 + lbl];
    s_clsls = nll * objf;
  }
  {
    int wv = tid >> 6, ln = tid & 63;
    float vals[6] = { s_obj, s_bce, s_bcecnt, s_objls, s_boxls, s_clsls };
    #pragma unroll
    for (int ci = 0; ci < 6; ++ci) {
      float v = wredf(vals[ci]);
      if (ln == 0) ry[ci * 6 + wv] = v;
    }
  }

  // ---- valid bit for step tid (recomputed; only w/h chain matters) ----
  unsigned vld, ufx, ufy, usx, usy; float ulv;
  step_params(tid, pred, anc, &vld, &ulv, &ufx, &ufy, &usx, &usy);

  __syncthreads();
  if (tid < 36) {
    int ch = tid / 6, comp = tid % 6;
    double s = 0.0;
    for (int t = ch * 64; t < ch * 64 + 64; ++t) s += sd[t * 6 + comp];
    chunk[tid] = s;
  }
  __syncthreads();

  int t = tid;
  int ch = t >> 6;
  double P[6];
  #pragma unroll
  for (int comp = 0; comp < 6; ++comp) {
    double s = 0.0;
    for (int cc = 0; cc < ch; ++cc) s += chunk[cc * 6 + comp];
    for (int tt = (ch << 6); tt <= t; ++tt) s += sd[tt * 6 + comp];
    P[comp] = s;   // inclusive prefix: sums AFTER step t's paint
  }
  double lossd = 0.0, cntd = 0.0;
  {
    double n = P[0], Sg = P[1], Sg2 = P[2];
    double mean = Sg / fmax(n, 1.0);
    double var = (Sg2 - 2.0 * mean * Sg + n * mean * mean) / fmax(n - 1.0, 1.0);
    double Dg = var + 0.15 * mean * mean;
    double pl = 10.0 * sqrt(fmax(Dg, 1e-30));
    if (vld && n >= 2.0) { lossd += pl; cntd += 1.0; }
  }
  {
    double n = P[3], Sg = P[4], Sg2 = P[5];
    double mean = Sg / fmax(n, 1.0);
    double var = (Sg2 - 2.0 * mean * Sg + n * mean * mean) / fmax(n - 1.0, 1.0);
    double Dg = var + 0.15 * mean * mean;
    double pl = 10.0 * sqrt(fmax(Dg, 1e-30));
    if (vld && n >= 2.0) { lossd += pl; cntd += 1.0; }
  }
  int wv = tid >> 6, ln = tid & 63;
  double L = wredd(lossd), C = wredd(cntd);
  if (ln == 0) { rl[wv] = L; rc[wv] = C; }
  __syncthreads();
  if (tid == 0) {
    double totL = 0.0, totC = 0.0;
    for (int i = 0; i < 6; ++i) { totL += rl[i]; totC += rc[i]; }
    float yolo[6];
    #pragma unroll
    for (int ci = 0; ci < 6; ++ci) {
      float s = 0.0f;
      for (int w2 = 0; w2 < 6; ++w2) s += ry[ci * 6 + w2];
      yolo[ci] = s;
    }
    float dl = (float)(totL / fmax(totC, 1.0));
    float nobj = fmaxf(yolo[0], 1.0f);
    float noo  = yolo[1] / fmaxf(yolo[2], 1.0f);
    float objl = yolo[3] / nobj;
    float boxl = yolo[4] / (nobj * 4.0f);
    float clsl = yolo[5] / nobj;
    out[0] = 10.0f * boxl + objl + 10.0f * noo + clsl + dl;
  }
}

extern "C" void kernel_launch(void* const* d_in, const int* in_sizes, int n_in,
                              void* d_out, int out_size, void* d_ws, size_t ws_size,
                              hipStream_t stream) {
  const float* pred  = (const float*)d_in[0];
  const float* tgt   = (const float*)d_in[1];
  const float* anc   = (const float*)d_in[2];
  const float* depth = (const float*)d_in[3];

  float* scratch = (float*)d_ws;                                   // NB*NE floats = 4.72 MB
  double* reduced = (double*)((char*)d_ws + (size_t)NB * NE * sizeof(float));  // NE doubles

  hipLaunchKernelGGL(yolo_kB, dim3(NB), dim3(256), 0, stream, pred, anc, depth, scratch);
  hipLaunchKernelGGL(yolo_kR, dim3(NE / 4), dim3(256), 0, stream, scratch, reduced);
  hipLaunchKernelGGL(yolo_kC, dim3(1), dim3(384), 0, stream, pred, tgt, anc, reduced, (float*)d_out);
}

// Round 6
// 122.197 us; speedup vs baseline: 2.0652x; 1.1584x over previous
//
#include <hip/hip_runtime.h>
#include <cmath>

#define BN 2
#define AN 3
#define SN 8
#define CN 20
#define IMGN 256
#define NSTEP 384   // A*S*S*B steps in scan order (k,i,j,b)
#define PRED_C 26   // 6 + C
#define NE (NSTEP * 6)
#define NB (BN * IMGN)   // 512 kB blocks, one row-unit each
#define NSB (NSTEP / BN) // 192 steps per batch

__device__ __forceinline__ float wredf(float v){
  #pragma unroll
  for (int o = 32; o; o >>= 1) v += __shfl_xor(v, o);
  return v;
}
__device__ __forceinline__ double wredd(double v){
  #pragma unroll
  for (int o = 32; o; o >>= 1) v += __shfl_xor(v, o);
  return v;
}
// rocPRIM-style gfx9 DPP wave sum: result valid in lane 63. Pure VALU, no LDS pipe.
// (correctness HW-verified: rounds 4/5 absmax 0.0)
__device__ __forceinline__ float wsum_dpp(float x){
  x += __int_as_float(__builtin_amdgcn_update_dpp(0, __float_as_int(x), 0x111, 0xf, 0xf, false)); // row_shr:1
  x += __int_as_float(__builtin_amdgcn_update_dpp(0, __float_as_int(x), 0x112, 0xf, 0xf, false)); // row_shr:2
  x += __int_as_float(__builtin_amdgcn_update_dpp(0, __float_as_int(x), 0x114, 0xf, 0xf, false)); // row_shr:4
  x += __int_as_float(__builtin_amdgcn_update_dpp(0, __float_as_int(x), 0x118, 0xf, 0xf, false)); // row_shr:8
  x += __int_as_float(__builtin_amdgcn_update_dpp(0, __float_as_int(x), 0x142, 0xa, 0xf, false)); // row_bcast:15
  x += __int_as_float(__builtin_amdgcn_update_dpp(0, __float_as_int(x), 0x143, 0xc, 0xf, false)); // row_bcast:31
  return x;
}
__device__ __forceinline__ int finitef(float x){
  return (__float_as_uint(x) & 0x7f800000u) != 0x7f800000u;
}
// exact replica of reference _axis_mask index computation (f32 trunc + negative wrap)
__device__ __forceinline__ unsigned axism(float lo, float hi){
  float lof = truncf(fminf(fmaxf(lo, -1e9f), 1e9f));
  float hif = truncf(fminf(fmaxf(hi, -1e9f), 1e9f));
  int l = (int)lof, h = (int)hif;
  l = (l < 0) ? max(IMGN + l, 0) : min(l, IMGN);
  h = (h < 0) ? max(IMGN + h, 0) : min(h, IMGN);
  return (unsigned)l | ((unsigned)h << 16);
}

// per-step scan parameters; scan order t = ((k*S + i)*S + j)*B + b
__device__ __forceinline__ void step_params(int t, const float* __restrict__ pred,
                                            const float* __restrict__ anc,
                                            unsigned* valid, float* lv,
                                            unsigned* fx, unsigned* fy,
                                            unsigned* sx, unsigned* sy){
  int b = t % BN;
  int j = (t / BN) % SN;
  int i = (t / (BN * SN)) % SN;
  int k = t / (BN * SN * SN);
  const float* pc = pred + (size_t)((((b * AN + k) * SN + i) * SN + j)) * PRED_C;
  float x = pc[1], y = pc[2], wv = pc[3], hv = pc[4], v = pc[5];
  float aw = anc[2 * k], ah = anc[2 * k + 1];
  // xy gets sigmoid applied (k+2) times total (1 before loop + k+1 in loop)
  for (int m = 0; m < k + 2; ++m) {
    x = 1.0f / (1.0f + expf(-x));
    y = 1.0f / (1.0f + expf(-y));
  }
  // wh: (k+1) iterations of exp(.)*anchor[k], in f32 (overflow -> inf -> invalid)
  for (int m = 0; m < k + 1; ++m) {
    wv = expf(wv) * aw;
    hv = expf(hv) * ah;
  }
  float cx = (x + (float)j) / 8.0f * 256.0f;
  float cy = (y + (float)i) / 8.0f * 256.0f;
  float w  = wv / 8.0f * 256.0f;
  float h  = hv / 8.0f * 256.0f;
  *valid = (w > 0.0f) && (h > 0.0f) && finitef(w) && finitef(h);
  *lv = logf(fmaxf(1.0f, v));
  // NOTE reference quirk: x-mask (from cx,w) indexes dp's ROW axis, y-mask the COL axis
  *fx = axism(cx - w / 2.0f, cx + w / 2.0f);
  *fy = axism(cy - h / 2.0f, cy + h / 2.0f);
  *sx = axism(cx - w / 4.0f, cx + w / 4.0f);
  *sy = axism(cy - h / 4.0f, cy + h / 4.0f);
}

// ---------------- Kernel B: per-pixel step scan -> per-block per-step delta partials ----------------
// one row-unit per block; per-WAVE compacted step lists (row + col-window filtered);
// sink = per-block LDS accumulator; one coalesced 9216 B scratch write per block.
__global__ __launch_bounds__(256) void yolo_kB(const float* __restrict__ pred,
                                               const float* __restrict__ anc,
                                               const float* __restrict__ depth,
                                               float* __restrict__ scratch){
  __shared__ uint2    s_rxx[NSTEP];        // (fx, sx) row-bound packs
  __shared__ uint2    s_cyy[NSTEP];        // (fy, sy) col-bound packs
  __shared__ float    s_lv[NSTEP];
  __shared__ unsigned s_list[4][NSB];      // per-wave compacted active steps (ordered)
  __shared__ int      s_nact[4];
  __shared__ float    s_acc[NE];           // per-block accumulator (LDS atomics, 4 writers max)

  int tid = threadIdx.x;
  for (int t = tid; t < NSTEP; t += 256) {
    unsigned vld, fx, fy, sx, sy; float lv;
    step_params(t, pred, anc, &vld, &lv, &fx, &fy, &sx, &sy);
    if (!vld) { fx = 0xFFFFu; sx = 0xFFFFu; }   // lo=0xFFFF,hi=0 -> empty row range
    s_rxx[t] = make_uint2(fx, sx);
    s_cyy[t] = make_uint2(fy, sy);
    s_lv[t] = lv;
  }
  for (int e = tid; e < NE; e += 256) s_acc[e] = 0.0f;
  __syncthreads();

  int ru = blockIdx.x;          // one row-unit per block
  int b = ru >> 8, r = ru & 255;
  int c = tid, ln = tid & 63, w = tid >> 6;
  int wlo = w * 64, whi = wlo + 64;   // this wave's col window

  // per-wave ordered compaction: keep steps that touch row r AND this wave's col window
  {
    int cnt = 0;
    #pragma unroll
    for (int g = 0; g < 3; ++g) {
      int m = g * 64 + ln;                 // m in [0,192)
      int t = b + 2 * m;                   // steps of batch b, increasing order
      uint2 rx = s_rxx[t];
      uint2 cy = s_cyy[t];
      bool rowF = (r >= (int)(rx.x & 0xffffu)) && (r < (int)(rx.x >> 16));
      bool rowS = (r >= (int)(rx.y & 0xffffu)) && (r < (int)(rx.y >> 16));
      bool fF = rowF && ((int)(cy.x & 0xffffu) < whi) && ((int)(cy.x >> 16) > wlo);
      bool fS = rowS && ((int)(cy.y & 0xffffu) < whi) && ((int)(cy.y >> 16) > wlo);
      bool f = fF || fS;
      unsigned long long msk = __ballot(f);
      int pos = (int)__popcll(msk & ((1ull << ln) - 1ull));
      if (f) s_list[w][cnt + pos] = (unsigned)t | (fF ? 512u : 0u) | (fS ? 1024u : 0u);
      cnt += (int)__popcll(msk);
    }
    if (ln == 0) s_nact[w] = cnt;
  }

  float dt = depth[(size_t)ru * IMGN + c];
  bool okp = dt >= 1.0f;
  float ldt = okp ? logf(dt) : 0.0f;
  __syncthreads();
  int nact = s_nact[w];

  // paint-state: lvF/lvS start at ldt -> first paint and repaint share one formula:
  //   d1 = lv - lvF;  d2 = (lv-ldt)^2 - (lvF-ldt)^2 = d1*(lv + lvF - 2*ldt)
  bool hF = false, hS = false;        // only needed for first-paint counts
  float lvF = ldt, lvS = ldt;
  float ldt2 = 2.0f * ldt;
  #pragma unroll 2
  for (int idx = 0; idx < nact; ++idx) {
    unsigned ent = s_list[w][idx];
    int t = (int)(ent & 511u);
    uint2 cyb = s_cyy[t];
    float lv = s_lv[t];
    bool inF = (ent & 512u)  && okp && (c >= (int)(cyb.x & 0xffffu)) && (c < (int)(cyb.x >> 16));
    bool inS = (ent & 1024u) && okp && (c >= (int)(cyb.y & 0xffffu)) && (c < (int)(cyb.y >> 16));
    unsigned long long mF = __ballot(inF && !hF);   // first paints (pre-update)
    unsigned long long mS = __ballot(inS && !hS);
    hF |= inF; hS |= inS;
    float d1 = inF ? (lv - lvF) : 0.0f;
    float d2 = d1 * (lv + lvF - ldt2);
    lvF = inF ? lv : lvF;
    float e1 = inS ? (lv - lvS) : 0.0f;
    float e2 = e1 * (lv + lvS - ldt2);
    lvS = inS ? lv : lvS;
    d1 = wsum_dpp(d1); d2 = wsum_dpp(d2);
    e1 = wsum_dpp(e1); e2 = wsum_dpp(e2);
    if (ln == 63) {
      float* base = s_acc + t * 6;
      float c0 = (float)__popcll(mF), c3 = (float)__popcll(mS);
      if (c0 != 0.f) atomicAdd(base + 0, c0);
      if (d1 != 0.f) atomicAdd(base + 1, d1);
      if (d2 != 0.f) atomicAdd(base + 2, d2);
      if (c3 != 0.f) atomicAdd(base + 3, c3);
      if (e1 != 0.f) atomicAdd(base + 4, e1);
      if (e2 != 0.f) atomicAdd(base + 5, e2);
    }
  }
  __syncthreads();
  // contiguous coalesced write: 9216 B per block
  for (int e = tid; e < NE; e += 256)
    scratch[(size_t)blockIdx.x * NE + e] = s_acc[e];
}

// ---------------- Kernel R: parallel reduce over kB blocks (COALESCED) ----------------
// grid = NE/64 = 36 blocks x 256 threads. Block g owns e in [g*64, g*64+64);
// lane ln -> e = g*64+ln (lane-contiguous); wave w sums bk in [w*128, w*128+128).
__global__ __launch_bounds__(256) void yolo_kR(const float* __restrict__ scratch,
                                               double* __restrict__ reduced){
  __shared__ double part[4][64];
  int ln = threadIdx.x & 63, w = threadIdx.x >> 6;
  int e = blockIdx.x * 64 + ln;
  double s = 0.0;
  for (int bk = w * (NB / 4); bk < (w + 1) * (NB / 4); ++bk)
    s += (double)scratch[(size_t)bk * NE + e];
  part[w][ln] = s;
  __syncthreads();
  if (w == 0)
    reduced[e] = part[0][ln] + part[1][ln] + part[2][ln] + part[3][ln];
}

// ---------------- Kernel C: YOLO losses + prefix over steps + final loss ----------------
__global__ __launch_bounds__(384) void yolo_kC(const float* __restrict__ pred,
                                               const float* __restrict__ tgt,
                                               const float* __restrict__ anc,
                                               const double* __restrict__ reduced,
                                               float* __restrict__ out){
  __shared__ double sd[NE];
  __shared__ double chunk[6 * 6];     // [chunkIdx][comp], chunks of 64 steps
  __shared__ double rl[6], rc[6];
  __shared__ float  ry[6 * 6];
  int tid = threadIdx.x;
  for (int e = tid; e < NE; e += 384) sd[e] = reduced[e];

  // ---- YOLO losses; cell order (b,a,i,j) ----
  float s_obj, s_bce, s_bcecnt, s_objls, s_boxls, s_clsls;
  {
    int t = tid;
    int j = t % SN;
    int i = (t / SN) % SN;
    int a = (t / (SN * SN)) % AN;
    int b = t / (SN * SN * AN);
    const float* pc = pred + (size_t)((((b * AN + a) * SN + i) * SN + j)) * PRED_C;
    const float* tc = tgt  + (size_t)((((b * AN + a) * SN + i) * SN + j)) * 6;
    float t0 = tc[0];
    float objf  = (t0 == 1.0f) ? 1.0f : 0.0f;
    float noobj = (t0 == 0.0f) ? 1.0f : 0.0f;
    float p0 = pc[0];
    float l = fmaxf(p0, 0.0f) - p0 * t0 + log1pf(expf(-fabsf(p0)));
    s_bce = l * noobj; s_bcecnt = noobj; s_obj = objf;
    float aw = anc[2 * a], ah = anc[2 * a + 1];
    float sxp = 1.0f / (1.0f + expf(-pc[1]));
    float syp = 1.0f / (1.0f + expf(-pc[2]));
    float bw = expf(pc[3]) * aw, bh = expf(pc[4]) * ah;
    float ax1 = sxp - bw * 0.5f, ax2 = sxp + bw * 0.5f;
    float ay1 = syp - bh * 0.5f, ay2 = syp + bh * 0.5f;
    float bx1 = tc[1] - tc[3] * 0.5f, bx2 = tc[1] + tc[3] * 0.5f;
    float by1 = tc[2] - tc[4] * 0.5f, by2 = tc[2] + tc[4] * 0.5f;
    float iw = fmaxf(fminf(ax2, bx2) - fmaxf(ax1, bx1), 0.0f);
    float ih = fmaxf(fminf(ay2, by2) - fmaxf(ay1, by1), 0.0f);
    float inter = iw * ih;
    float areaA = fabsf((ax2 - ax1) * (ay2 - ay1));
    float areaB = fabsf((bx2 - bx1) * (by2 - by1));
    float iou = inter / (areaA + areaB - inter + 1e-6f);
    float sp0 = 1.0f / (1.0f + expf(-p0));
    float od = sp0 - iou * t0;
    s_objls = od * od * objf;
    float dx = sxp - tc[1], dy = syp - tc[2];
    float dw = pc[3] - logf(1e-16f + tc[3] / aw);
    float dh = pc[4] - logf(1e-16f + tc[4] / ah);
    s_boxls = (dx * dx + dy * dy + dw * dw + dh * dh) * objf;
    int lbl = (int)tc[5];
    float mx = -INFINITY;
    for (int c = 0; c < CN; ++c) mx = fmaxf(mx, pc[6 + c]);
    float se = 0.0f;
    for (int c = 0; c < CN; ++c) se += expf(pc[6 + c] - mx);
    float nll = mx + logf(se) - pc[6 + lbl];
    s_clsls = nll * objf;
  }
  {
    int wv = tid >> 6, ln = tid & 63;
    float vals[6] = { s_obj, s_bce, s_bcecnt, s_objls, s_boxls, s_clsls };
    #pragma unroll
    for (int ci = 0; ci < 6; ++ci) {
      float v = wredf(vals[ci]);
      if (ln == 0) ry[ci * 6 + wv] = v;
    }
  }

  // ---- valid bit for step tid (recomputed; only w/h chain matters) ----
  unsigned vld, ufx, ufy, usx, usy; float ulv;
  step_params(tid, pred, anc, &vld, &ulv, &ufx, &ufy, &usx, &usy);

  __syncthreads();
  // chunk sums: wave ch reduces chunk ch (64 steps) for all 6 comps in parallel
  {
    int ch = tid >> 6, ln = tid & 63;
    #pragma unroll
    for (int comp = 0; comp < 6; ++comp) {
      double v = wredd(sd[(ch * 64 + ln) * 6 + comp]);
      if (ln == 0) chunk[ch * 6 + comp] = v;
    }
  }
  __syncthreads();

  int t = tid;
  int ch = t >> 6;
  double P[6];
  #pragma unroll
  for (int comp = 0; comp < 6; ++comp) {
    double s = 0.0;
    for (int cc = 0; cc < ch; ++cc) s += chunk[cc * 6 + comp];
    for (int tt = (ch << 6); tt <= t; ++tt) s += sd[tt * 6 + comp];
    P[comp] = s;   // inclusive prefix: sums AFTER step t's paint
  }
  double lossd = 0.0, cntd = 0.0;
  {
    double n = P[0], Sg = P[1], Sg2 = P[2];
    double mean = Sg / fmax(n, 1.0);
    double var = (Sg2 - 2.0 * mean * Sg + n * mean * mean) / fmax(n - 1.0, 1.0);
    double Dg = var + 0.15 * mean * mean;
    double pl = 10.0 * sqrt(fmax(Dg, 1e-30));
    if (vld && n >= 2.0) { lossd += pl; cntd += 1.0; }
  }
  {
    double n = P[3], Sg = P[4], Sg2 = P[5];
    double mean = Sg / fmax(n, 1.0);
    double var = (Sg2 - 2.0 * mean * Sg + n * mean * mean) / fmax(n - 1.0, 1.0);
    double Dg = var + 0.15 * mean * mean;
    double pl = 10.0 * sqrt(fmax(Dg, 1e-30));
    if (vld && n >= 2.0) { lossd += pl; cntd += 1.0; }
  }
  int wv = tid >> 6, ln = tid & 63;
  double L = wredd(lossd), C = wredd(cntd);
  if (ln == 0) { rl[wv] = L; rc[wv] = C; }
  __syncthreads();
  if (tid == 0) {
    double totL = 0.0, totC = 0.0;
    for (int i = 0; i < 6; ++i) { totL += rl[i]; totC += rc[i]; }
    float yolo[6];
    #pragma unroll
    for (int ci = 0; ci < 6; ++ci) {
      float s = 0.0f;
      for (int w2 = 0; w2 < 6; ++w2) s += ry[ci * 6 + w2];
      yolo[ci] = s;
    }
    float dl = (float)(totL / fmax(totC, 1.0));
    float nobj = fmaxf(yolo[0], 1.0f);
    float noo  = yolo[1] / fmaxf(yolo[2], 1.0f);
    float objl = yolo[3] / nobj;
    float boxl = yolo[4] / (nobj * 4.0f);
    float clsl = yolo[5] / nobj;
    out[0] = 10.0f * boxl + objl + 10.0f * noo + clsl + dl;
  }
}

extern "C" void kernel_launch(void* const* d_in, const int* in_sizes, int n_in,
                              void* d_out, int out_size, void* d_ws, size_t ws_size,
                              hipStream_t stream) {
  const float* pred  = (const float*)d_in[0];
  const float* tgt   = (const float*)d_in[1];
  const float* anc   = (const float*)d_in[2];
  const float* depth = (const float*)d_in[3];

  float* scratch = (float*)d_ws;                                   // NB*NE floats = 4.72 MB
  double* reduced = (double*)((char*)d_ws + (size_t)NB * NE * sizeof(float));  // NE doubles

  hipLaunchKernelGGL(yolo_kB, dim3(NB), dim3(256), 0, stream, pred, anc, depth, scratch);
  hipLaunchKernelGGL(yolo_kR, dim3(NE / 64), dim3(256), 0, stream, scratch, reduced);
  hipLaunchKernelGGL(yolo_kC, dim3(1), dim3(384), 0, stream, pred, tgt, anc, reduced, (float*)d_out);
}